// Round 1
// baseline (546.030 us; speedup 1.0000x reference)
//
#include <hip/hip_runtime.h>
#include <hip/hip_bf16.h>

#define F 2048
#define MB 16384
#define BM 128
#define BN 128
#define BK 64
#define APAD 72   // A-tile LDS row stride in bf16 elems (64 + 8 pad -> 2-way bank conflict = free)

typedef short bf16x8 __attribute__((ext_vector_type(8)));  // 8 bf16 (4 VGPRs), MFMA A/B frag
typedef float f32x4 __attribute__((ext_vector_type(4)));   // MFMA C/D frag

__device__ __forceinline__ unsigned short bf_bits(__hip_bfloat16 h) {
    return __builtin_bit_cast(unsigned short, h);
}

// ---------------- build transposed upper-tri B planes (hi/lo bf16) ----------------
// Bt[j2*F + j1] = bw[pair(j1,j2)] if j1<j2 else 0.  Transposed layout so the GEMM
// B-operand (k = j1) is contiguous per column j2.
__global__ __launch_bounds__(256) void build_bt(const float* __restrict__ bw,
                                                unsigned short* __restrict__ bt_hi,
                                                unsigned short* __restrict__ bt_lo) {
    int idx = blockIdx.x * 256 + threadIdx.x;   // idx over F*F, row-major [j2][j1]
    int j2 = idx >> 11;
    int j1 = idx & (F - 1);
    float v = 0.f;
    if (j1 < j2) {
        int k = j1 * F - ((j1 * (j1 + 1)) >> 1) + (j2 - j1 - 1);
        v = bw[k];
    }
    __hip_bfloat16 h = __float2bfloat16(v);
    float hf = __bfloat162float(h);
    __hip_bfloat16 l = __float2bfloat16(v - hf);
    bt_hi[idx] = bf_bits(h);
    bt_lo[idx] = bf_bits(l);
}

// ---------------- main GEMM: y = x * B (upper-tri), fused epilogue ----------------
// cross_acc[b] += sum_c (y[b,c] + w[c]) * x[b,c]   (per column-block -> includes x.w term)
__global__ __launch_bounds__(256, 2) void poly2_gemm(
        const float* __restrict__ x,
        const unsigned short* __restrict__ bt_hi,
        const unsigned short* __restrict__ bt_lo,
        const float* __restrict__ w,
        float* __restrict__ cross_acc) {
    extern __shared__ unsigned short smem[];
    unsigned short* sA_hi = smem;                      // [BM][APAD]
    unsigned short* sA_lo = sA_hi + BM * APAD;
    unsigned short* sB_hi = sA_lo + BM * APAD;         // [BN][BK], chunk-xor swizzled
    unsigned short* sB_lo = sB_hi + BN * BK;

    const int tid  = threadIdx.x;
    const int lane = tid & 63;
    const int wid  = tid >> 6;
    const int wm   = wid >> 1;      // 2x2 wave grid, each wave 64x64 out
    const int wn   = wid & 1;
    const int lr   = lane & 15;
    const int lg   = lane >> 4;

    const int mt = blockIdx.x >> 4;
    const int nt = 15 - (blockIdx.x & 15);   // high-work blocks first
    const int m0 = mt * BM;
    const int n0 = nt * BN;
    const int ktiles = 2 * (nt + 1);         // triangular skip: only kt*64 < (nt+1)*128

    f32x4 acc[4][4] = {};

    for (int kt = 0; kt < ktiles; ++kt) {
        const int k0 = kt * BK;

        // ---- stage B planes: global_load_lds, 16B/lane, chunk-xor swizzle ----
        // LDS slot q (16B chunks): c = q>>3 (col), slot = q&7 holds data chunk (q&7)^(c&7)
#pragma unroll
        for (int i = 0; i < 4; ++i) {
            int q = i * 256 + tid;
            int c = q >> 3;
            int ch = (q & 7) ^ (c & 7);
            const unsigned short* ghi = bt_hi + (size_t)(n0 + c) * F + (k0 + ch * 8);
            const unsigned short* glo = bt_lo + (size_t)(n0 + c) * F + (k0 + ch * 8);
            unsigned short* lhi = sB_hi + (q & ~63) * 8;   // wave-uniform base + lane*16B
            unsigned short* llo = sB_lo + (q & ~63) * 8;
            __builtin_amdgcn_global_load_lds(
                (const __attribute__((address_space(1))) unsigned int*)ghi,
                (__attribute__((address_space(3))) unsigned int*)lhi, 16, 0, 0);
            __builtin_amdgcn_global_load_lds(
                (const __attribute__((address_space(1))) unsigned int*)glo,
                (__attribute__((address_space(3))) unsigned int*)llo, 16, 0, 0);
        }

        // ---- stage A: fp32 -> bf16 hi/lo split, reg-staged into padded LDS ----
#pragma unroll
        for (int i = 0; i < 8; ++i) {
            int f   = i * 256 + tid;
            int row = f >> 4;            // 16 float4 per 64-elem row
            int k   = (f & 15) * 4;
            float4 v = *(const float4*)(x + (size_t)(m0 + row) * F + (k0 + k));
            __hip_bfloat16 h0 = __float2bfloat16(v.x), h1 = __float2bfloat16(v.y),
                           h2 = __float2bfloat16(v.z), h3 = __float2bfloat16(v.w);
            __hip_bfloat16 l0 = __float2bfloat16(v.x - __bfloat162float(h0));
            __hip_bfloat16 l1 = __float2bfloat16(v.y - __bfloat162float(h1));
            __hip_bfloat16 l2 = __float2bfloat16(v.z - __bfloat162float(h2));
            __hip_bfloat16 l3 = __float2bfloat16(v.w - __bfloat162float(h3));
            uint2 hp, lp;
            hp.x = (unsigned)bf_bits(h0) | ((unsigned)bf_bits(h1) << 16);
            hp.y = (unsigned)bf_bits(h2) | ((unsigned)bf_bits(h3) << 16);
            lp.x = (unsigned)bf_bits(l0) | ((unsigned)bf_bits(l1) << 16);
            lp.y = (unsigned)bf_bits(l2) | ((unsigned)bf_bits(l3) << 16);
            *(uint2*)&sA_hi[row * APAD + k] = hp;
            *(uint2*)&sA_lo[row * APAD + k] = lp;
        }

        __syncthreads();   // drains vmcnt (global_load_lds) + lgkm

        // ---- compute: 3-term hi/lo MFMA, 96 MFMA per K-step per wave ----
#pragma unroll
        for (int kk = 0; kk < 2; ++kk) {
            bf16x8 ah[4], al[4], bh[4], bl[4];
#pragma unroll
            for (int m = 0; m < 4; ++m) {
                int row  = wm * 64 + m * 16 + lr;
                int koff = kk * 32 + lg * 8;
                ah[m] = *(const bf16x8*)&sA_hi[row * APAD + koff];
                al[m] = *(const bf16x8*)&sA_lo[row * APAD + koff];
            }
#pragma unroll
            for (int n = 0; n < 4; ++n) {
                int c  = wn * 64 + n * 16 + lr;
                int ch = (kk * 4 + lg) ^ (c & 7);
                bh[n] = *(const bf16x8*)&sB_hi[c * 64 + ch * 8];
                bl[n] = *(const bf16x8*)&sB_lo[c * 64 + ch * 8];
            }
#pragma unroll
            for (int m = 0; m < 4; ++m)
#pragma unroll
                for (int n = 0; n < 4; ++n) {
                    acc[m][n] = __builtin_amdgcn_mfma_f32_16x16x32_bf16(ah[m], bh[n], acc[m][n], 0, 0, 0);
                    acc[m][n] = __builtin_amdgcn_mfma_f32_16x16x32_bf16(ah[m], bl[n], acc[m][n], 0, 0, 0);
                    acc[m][n] = __builtin_amdgcn_mfma_f32_16x16x32_bf16(al[m], bh[n], acc[m][n], 0, 0, 0);
                }
        }
        __syncthreads();
    }

    // ---- epilogue: (y + w) dot x per row, 16-lane shuffle reduce, atomic accumulate ----
#pragma unroll
    for (int m = 0; m < 4; ++m) {
#pragma unroll
        for (int r = 0; r < 4; ++r) {
            int grow = m0 + wm * 64 + m * 16 + lg * 4 + r;
            float sum = 0.f;
#pragma unroll
            for (int n = 0; n < 4; ++n) {
                int gcol = n0 + wn * 64 + n * 16 + lr;
                float y = acc[m][n][r] + w[gcol];
                sum += y * x[(size_t)grow * F + gcol];
            }
            sum += __shfl_xor(sum, 1);
            sum += __shfl_xor(sum, 2);
            sum += __shfl_xor(sum, 4);
            sum += __shfl_xor(sum, 8);
            if (lr == 0) atomicAdd(&cross_acc[grow], sum);
        }
    }
}

// ---------------- final sigmoid ----------------
__global__ __launch_bounds__(256) void finish_sigmoid(const float* __restrict__ cross,
                                                      const float* __restrict__ w0,
                                                      float* __restrict__ out) {
    int b = blockIdx.x * 256 + threadIdx.x;
    float z = cross[b] + w0[0];
    out[b] = 1.f / (1.f + expf(-z));
}

extern "C" void kernel_launch(void* const* d_in, const int* in_sizes, int n_in,
                              void* d_out, int out_size, void* d_ws, size_t ws_size,
                              hipStream_t stream) {
    const float* x  = (const float*)d_in[0];
    const float* w0 = (const float*)d_in[1];
    const float* w  = (const float*)d_in[2];
    const float* bw = (const float*)d_in[3];
    float* out = (float*)d_out;

    // ws layout: [cross_acc: MB f32][bt_hi: F*F bf16][bt_lo: F*F bf16]  (~16.9 MB)
    float* cross = (float*)d_ws;
    unsigned short* bt_hi = (unsigned short*)((char*)d_ws + (size_t)MB * sizeof(float));
    unsigned short* bt_lo = bt_hi + (size_t)F * F;

    hipMemsetAsync(cross, 0, (size_t)MB * sizeof(float), stream);
    build_bt<<<F * F / 256, 256, 0, stream>>>(bw, bt_hi, bt_lo);
    size_t smem = (size_t)(2 * BM * APAD + 2 * BN * BK) * sizeof(unsigned short);
    poly2_gemm<<<dim3((MB / BM) * (F / BN)), 256, smem, stream>>>(x, bt_hi, bt_lo, w, cross);
    finish_sigmoid<<<MB / 256, 256, 0, stream>>>(cross, w0, out);
}

// Round 3
// 463.968 us; speedup vs baseline: 1.1769x; 1.1769x over previous
//
#include <hip/hip_runtime.h>
#include <hip/hip_bf16.h>

#define F 2048
#define MB 16384
#define BM 128
#define BN 128
#define BK 32
#define PLANE (BM * BK)   // 4096 shorts = 8 KB per plane

typedef short bf16x8 __attribute__((ext_vector_type(8)));  // 8 bf16 (4 VGPRs), MFMA A/B frag
typedef float f32x4 __attribute__((ext_vector_type(4)));   // MFMA C/D frag

static __device__ __forceinline__ unsigned short bfb(float v) {
    return __builtin_bit_cast(unsigned short, __float2bfloat16(v));
}
static __device__ __forceinline__ float bff(unsigned short u) {
    return __bfloat162float(__builtin_bit_cast(__hip_bfloat16, u));
}

// ---------------- build transposed upper-tri B planes (hi/lo bf16) ----------------
// Bt[j2*F + j1] = bw[pair(j1,j2)] if j1<j2 else 0.
__global__ __launch_bounds__(256) void build_bt(const float* __restrict__ bw,
                                                unsigned short* __restrict__ bt_hi,
                                                unsigned short* __restrict__ bt_lo) {
    int idx = blockIdx.x * 256 + threadIdx.x;   // idx over F*F, row-major [j2][j1]
    int j2 = idx >> 11;
    int j1 = idx & (F - 1);
    float v = 0.f;
    if (j1 < j2) {
        int k = j1 * F - ((j1 * (j1 + 1)) >> 1) + (j2 - j1 - 1);
        v = bw[k];
    }
    unsigned short h = bfb(v);
    bt_hi[idx] = h;
    bt_lo[idx] = bfb(v - bff(h));
}

// ---------------- main GEMM: y = x * B (upper-tri), fused epilogue ----------------
// 2-phase double-buffered; LDS: smem[buf][plane][PLANE], planes {Ah, Al, Bh, Bl},
// all chunk-xor swizzled: slot s (16B) of row r holds data chunk s ^ (r & 3).
__global__ __launch_bounds__(256, 2) void poly2_gemm(
        const float* __restrict__ x,
        const unsigned short* __restrict__ bt_hi,
        const unsigned short* __restrict__ bt_lo,
        const float* __restrict__ w,
        float* __restrict__ cross_acc) {
    extern __shared__ unsigned short smem[];

    const int tid  = threadIdx.x;
    const int lane = tid & 63;
    const int wid  = tid >> 6;
    const int wm   = wid >> 1;      // 2x2 wave grid, each wave 64x64 out
    const int wn   = wid & 1;
    const int lr   = lane & 15;
    const int lg   = lane >> 4;

    // work-descending order: 128 consecutive blocks share the same bt columns
    const int nt = 15 - (blockIdx.x >> 7);
    const int mt = blockIdx.x & 127;
    const int m0 = mt * BM;
    const int n0 = nt * BN;
    const int ktiles = 4 * (nt + 1);        // triangular skip: kt*32 < (nt+1)*128

    f32x4 acc[4][4] = {};

    // ---- staging helpers ----
    auto stageB = [&](int buf, int k0) {
        unsigned short* Bh = smem + buf * 4 * PLANE + 2 * PLANE;
        unsigned short* Bl = Bh + PLANE;
#pragma unroll
        for (int r = 0; r < 2; ++r) {
            int q = r * 256 + tid;
            int c = q >> 2, s = q & 3;
            int d = s ^ (c & 3);
            const unsigned short* ghi = bt_hi + (size_t)(n0 + c) * F + (k0 + d * 8);
            const unsigned short* glo = bt_lo + (size_t)(n0 + c) * F + (k0 + d * 8);
            unsigned short* dh = Bh + (q & ~63) * 8;   // wave-uniform base + lane*16B
            unsigned short* dl = Bl + (q & ~63) * 8;
            __builtin_amdgcn_global_load_lds(
                (const __attribute__((address_space(1))) unsigned int*)ghi,
                (__attribute__((address_space(3))) unsigned int*)dh, 16, 0, 0);
            __builtin_amdgcn_global_load_lds(
                (const __attribute__((address_space(1))) unsigned int*)glo,
                (__attribute__((address_space(3))) unsigned int*)dl, 16, 0, 0);
        }
    };
    auto loadA = [&](int k0, float4* av) {
#pragma unroll
        for (int r = 0; r < 2; ++r) {
            int q = r * 256 + tid;
            int row = q >> 2, d = q & 3;
            const float* src = x + (size_t)(m0 + row) * F + (k0 + d * 8);
            av[r * 2 + 0] = *(const float4*)(src);
            av[r * 2 + 1] = *(const float4*)(src + 4);
        }
    };
    auto writeA = [&](int buf, const float4* av) {
        unsigned short* Ah = smem + buf * 4 * PLANE;
        unsigned short* Al = Ah + PLANE;
#pragma unroll
        for (int r = 0; r < 2; ++r) {
            int q = r * 256 + tid;
            int row = q >> 2, d = q & 3, s = d ^ (row & 3);
            float vv[8] = {av[r*2].x, av[r*2].y, av[r*2].z, av[r*2].w,
                           av[r*2+1].x, av[r*2+1].y, av[r*2+1].z, av[r*2+1].w};
            unsigned hw[8], lw[8];
#pragma unroll
            for (int j = 0; j < 8; ++j) {
                unsigned short h = bfb(vv[j]);
                hw[j] = h;
                lw[j] = bfb(vv[j] - bff(h));
            }
            uint4 hp, lp;
            hp.x = hw[0] | (hw[1] << 16); hp.y = hw[2] | (hw[3] << 16);
            hp.z = hw[4] | (hw[5] << 16); hp.w = hw[6] | (hw[7] << 16);
            lp.x = lw[0] | (lw[1] << 16); lp.y = lw[2] | (lw[3] << 16);
            lp.z = lw[4] | (lw[5] << 16); lp.w = lw[6] | (lw[7] << 16);
            *(uint4*)&Ah[row * 32 + s * 8] = hp;
            *(uint4*)&Al[row * 32 + s * 8] = lp;
        }
    };

    // ---- prologue: fill buf 0 ----
    {
        float4 av[4];
        stageB(0, 0);
        loadA(0, av);
        writeA(0, av);
    }
    __syncthreads();

    int cur = 0;
    for (int kt = 0; kt < ktiles; ++kt) {
        const bool more = (kt + 1) < ktiles;
        float4 av[4];
        if (more) {                       // T14: issue loads early...
            stageB(cur ^ 1, (kt + 1) * BK);
            loadA((kt + 1) * BK, av);
        }

        // ---- compute current buffer ----
        unsigned short* Ah = smem + cur * 4 * PLANE;
        unsigned short* Al = Ah + PLANE;
        unsigned short* Bh = Al + PLANE;
        unsigned short* Bl = Bh + PLANE;
        const int sl = lg ^ (lr & 3);     // swizzled slot for data chunk lg
        bf16x8 ah[4], al[4], bh[4], bl[4];
#pragma unroll
        for (int m = 0; m < 4; ++m) {
            int row = wm * 64 + m * 16 + lr;
            ah[m] = *(const bf16x8*)&Ah[row * 32 + sl * 8];
            al[m] = *(const bf16x8*)&Al[row * 32 + sl * 8];
        }
#pragma unroll
        for (int n = 0; n < 4; ++n) {
            int c = wn * 64 + n * 16 + lr;
            bh[n] = *(const bf16x8*)&Bh[c * 32 + sl * 8];
            bl[n] = *(const bf16x8*)&Bl[c * 32 + sl * 8];
        }
#pragma unroll
        for (int m = 0; m < 4; ++m)
#pragma unroll
            for (int n = 0; n < 4; ++n) {
                acc[m][n] = __builtin_amdgcn_mfma_f32_16x16x32_bf16(ah[m], bh[n], acc[m][n], 0, 0, 0);
                acc[m][n] = __builtin_amdgcn_mfma_f32_16x16x32_bf16(ah[m], bl[n], acc[m][n], 0, 0, 0);
                acc[m][n] = __builtin_amdgcn_mfma_f32_16x16x32_bf16(al[m], bh[n], acc[m][n], 0, 0, 0);
            }

        if (more) writeA(cur ^ 1, av);    // ...convert + LDS-write late (hidden under MFMA)
        __syncthreads();
        cur ^= 1;
    }

    // ---- epilogue: (y + w) dot x per row, 16-lane shuffle reduce, atomic accumulate ----
#pragma unroll
    for (int m = 0; m < 4; ++m) {
#pragma unroll
        for (int r = 0; r < 4; ++r) {
            int grow = m0 + wm * 64 + m * 16 + lg * 4 + r;
            float sum = 0.f;
#pragma unroll
            for (int n = 0; n < 4; ++n) {
                int gcol = n0 + wn * 64 + n * 16 + lr;
                float y = acc[m][n][r] + w[gcol];
                sum += y * x[(size_t)grow * F + gcol];
            }
            sum += __shfl_xor(sum, 1);
            sum += __shfl_xor(sum, 2);
            sum += __shfl_xor(sum, 4);
            sum += __shfl_xor(sum, 8);
            if (lr == 0) atomicAdd(&cross_acc[grow], sum);
        }
    }
}

// ---------------- final sigmoid ----------------
__global__ __launch_bounds__(256) void finish_sigmoid(const float* __restrict__ cross,
                                                      const float* __restrict__ w0,
                                                      float* __restrict__ out) {
    int b = blockIdx.x * 256 + threadIdx.x;
    float z = cross[b] + w0[0];
    out[b] = 1.f / (1.f + expf(-z));
}

extern "C" void kernel_launch(void* const* d_in, const int* in_sizes, int n_in,
                              void* d_out, int out_size, void* d_ws, size_t ws_size,
                              hipStream_t stream) {
    const float* x  = (const float*)d_in[0];
    const float* w0 = (const float*)d_in[1];
    const float* w  = (const float*)d_in[2];
    const float* bw = (const float*)d_in[3];
    float* out = (float*)d_out;

    // ws layout: [cross_acc: MB f32][bt_hi: F*F bf16][bt_lo: F*F bf16]  (~16.9 MB)
    float* cross = (float*)d_ws;
    unsigned short* bt_hi = (unsigned short*)((char*)d_ws + (size_t)MB * sizeof(float));
    unsigned short* bt_lo = bt_hi + (size_t)F * F;

    hipMemsetAsync(cross, 0, (size_t)MB * sizeof(float), stream);
    build_bt<<<F * F / 256, 256, 0, stream>>>(bw, bt_hi, bt_lo);
    size_t smem = (size_t)(2 * 4 * PLANE) * sizeof(unsigned short);   // 64 KiB
    poly2_gemm<<<dim3((MB / BM) * (F / BN)), 256, smem, stream>>>(x, bt_hi, bt_lo, w, cross);
    finish_sigmoid<<<MB / 256, 256, 0, stream>>>(cross, w0, out);
}